// Round 4
// baseline (5289.875 us; speedup 1.0000x reference)
//
#include <hip/hip_runtime.h>
#include <hip/hip_bf16.h>

// Problem constants
#define B_    128
#define T_    512
#define IN_   128
#define H_    1024
#define OUT_  64
#define KTOT  1152          // IN_ + H_
#define GH    64            // hidden groups (16 units, 64 gate cols each)
#define GB    4             // batch groups (32 rows each)

typedef short bf16x8 __attribute__((ext_vector_type(8)));
typedef float f32x4  __attribute__((ext_vector_type(4)));

#define MFMA(a,b,c) __builtin_amdgcn_mfma_f32_16x16x32_bf16((a),(b),(c),0,0,0)

__device__ __forceinline__ unsigned short f2bf(float x) {
    unsigned int xi = __float_as_uint(x);
    unsigned int r  = (xi + 0x7fffu + ((xi >> 16) & 1u)) >> 16;
    return (unsigned short)r;
}

// ---------------------------------------------------------------------------
// Pack combined recurrent weights: Wp[c][k] bf16, c = gh*64 + unit_local*4 + gate
// gate 0,1,2 = f,i,z (kernel_fiz col gate*H + j); gate 3 = r (kernel_r col j)
// ---------------------------------------------------------------------------
__global__ void pack_weights(const float* __restrict__ kfiz, const float* __restrict__ kr,
                             const float* __restrict__ bfiz, const float* __restrict__ br,
                             unsigned short* __restrict__ Wp, float* __restrict__ biasp)
{
    const int c    = blockIdx.x;            // 0..4095
    const int gh   = c >> 6, nl = c & 63;
    const int j    = gh * 16 + (nl >> 2);
    const int gate = nl & 3;
    for (int k = threadIdx.x; k < KTOT; k += 256) {
        float v = (gate < 3) ? kfiz[(size_t)k * 3072 + gate * 1024 + j]
                             : kr[(size_t)k * 1024 + j];
        Wp[(size_t)c * KTOT + k] = f2bf(v);
    }
    if (threadIdx.x == 0)
        biasp[c] = (gate < 3) ? bfiz[gate * 1024 + j] : br[j];
}

// u (B,T,IN) fp32 -> Ubf (T,B,IN) bf16
__global__ void pack_u(const float* __restrict__ u, unsigned short* __restrict__ Ubf)
{
    size_t i = (size_t)blockIdx.x * 256 + threadIdx.x;   // < 8388608
    int t = (int)(i >> 14);
    int rem = (int)(i & 16383);
    int b = rem >> 7, k = rem & 127;
    Ubf[i] = f2bf(u[((size_t)b << 16) + ((size_t)t << 7) + k]);
}

// W_out (H,OUT) fp32 -> Wob[o][k] bf16
__global__ void pack_wout(const float* __restrict__ wo, unsigned short* __restrict__ Wob)
{
    const int o = blockIdx.x;               // 0..63
    for (int k = threadIdx.x; k < H_; k += 256)
        Wob[(size_t)o * H_ + k] = f2bf(wo[(size_t)k * OUT_ + o]);
}

// ---------------------------------------------------------------------------
// Persistent recurrent scan. Grid = 256 WGs x 512 threads (cooperative, 1/CU).
// WG (gb,gh): batch rows [gb*32,+32), hidden units [gh*16,+16) (64 gate cols).
// XCD swizzle: gb = (bid&7)>>1 -> each gb group lives on one XCD pair.
// Wave (0..7): mi = wave&1 (16-row half), nj = wave>>1 (16-col group).
// Weights register-resident; LDS used only for the 1 KB h-tile transpose.
// h exchange: epilogue -> LDS transpose -> wave0 stores 128 x 8B coalesced
// write-through (relaxed agent atomics). tid0 sets per-WG flag after a
// wave-local s_waitcnt(0) drains its own stores (no extra barrier needed).
// Consumers: wave0 polls the 64 producer flags in parallel (reads only).
// ---------------------------------------------------------------------------
__global__ void __launch_bounds__(512, 2)
lstm_scan(const float* __restrict__ x0,
          const unsigned short* __restrict__ Wp,
          const float* __restrict__ biasp,
          const unsigned short* __restrict__ Ubf,
          unsigned short* __restrict__ Hall,
          int* __restrict__ Flag)
{
    __shared__ unsigned short hT[32 * 16];    // 1 KB h-tile transpose buffer

    const int tid  = threadIdx.x;
    const int bid  = blockIdx.x;
    const int gb   = (bid & 7) >> 1;                 // XCD-pair -> one gb group
    const int gh   = ((bid & 1) << 5) | (bid >> 3);  // 0..63, unique per gb
    const int wave = tid >> 6;
    const int lane = tid & 63;
    const int mi   = wave & 1;
    const int nj   = wave >> 1;               // 0..3
    const int quad = lane >> 4;
    const int l15  = lane & 15;
    const int g    = l15 & 3;                 // gate id of this lane's column

    // Loop-invariant weights into registers: cols nj*16 + l15, k-chunk kk.
    bf16x8 wreg[36];
    {
        const unsigned short* wp = Wp + (size_t)(gh * 64 + nj * 16 + l15) * KTOT + quad * 8;
        #pragma unroll
        for (int kk = 0; kk < 36; ++kk)
            wreg[kk] = *reinterpret_cast<const bf16x8*>(wp + kk * 32);
    }
    const float bias = biasp[gh * 64 + nj * 16 + l15];

    const int rowBase = gb * 32 + mi * 16;
    const int j       = gh * 16 + nj * 4 + (l15 >> 2);

    // c-state (fp32, replicated across the 4 gate lanes of each unit)
    float cst[4];
    #pragma unroll
    for (int r = 0; r < 4; ++r)
        cst[r] = x0[(size_t)(rowBase + quad * 4 + r) * 2048 + 1024 + j];

    // h0 -> Hall[0] (write-through; one-time, scatter is fine here)
    {
        int m = tid >> 4, uu = tid & 15;      // 512 threads, 512 elems
        int b = gb * 32 + m, jj = gh * 16 + uu;
        unsigned short hv = f2bf(x0[(size_t)b * 2048 + jj]);
        __hip_atomic_store(&Hall[(size_t)b * H_ + jj], hv,
                           __ATOMIC_RELAXED, __HIP_MEMORY_SCOPE_AGENT);
    }
    __syncthreads();                           // vmcnt(0) drain per wave
    if (tid == 0)
        __hip_atomic_store(&Flag[(size_t)gb * 64 + gh], 1,
                           __ATOMIC_RELAXED, __HIP_MEMORY_SCOPE_AGENT);

    const int aRow = rowBase + l15;            // A-frag row (batch index)
    const unsigned short* aU  = Ubf  + (size_t)aRow * IN_ + quad * 8;
    const unsigned short* aHb = Hall + (size_t)aRow * H_  + quad * 8;

    for (int t = 0; t < T_; ++t) {
        // ---- u-part (independent of h[t]) ----
        f32x4 accA = {bias, bias, bias, bias};
        f32x4 accB = {0.f, 0.f, 0.f, 0.f};
        {
            const unsigned short* au = aU + (size_t)t * (B_ * IN_);
            bf16x8 a0 = *reinterpret_cast<const bf16x8*>(au);
            bf16x8 a1 = *reinterpret_cast<const bf16x8*>(au + 32);
            bf16x8 a2 = *reinterpret_cast<const bf16x8*>(au + 64);
            bf16x8 a3 = *reinterpret_cast<const bf16x8*>(au + 96);
            accA = MFMA(a0, wreg[0], accA);
            accB = MFMA(a1, wreg[1], accB);
            accA = MFMA(a2, wreg[2], accA);
            accB = MFMA(a3, wreg[3], accB);
        }

        // ---- wait for h[t]: 64-lane parallel flag poll (reads only) ----
        if (wave == 0) {
            const int* fp = Flag + ((size_t)t * GB + gb) * 64 + lane;
            int v = __hip_atomic_load(fp, __ATOMIC_RELAXED, __HIP_MEMORY_SCOPE_AGENT);
            while (!__all(v != 0))
                v = __hip_atomic_load(fp, __ATOMIC_RELAXED, __HIP_MEMORY_SCOPE_AGENT);
        }
        __syncthreads();                       // B1

        // ---- h-part: 32 chunks, 2x8 register double-buffer ----
        const unsigned short* ah = aHb + (size_t)t * (B_ * H_);
        bf16x8 bufA[8], bufB[8];
        #pragma unroll
        for (int i = 0; i < 8; ++i) bufA[i] = *reinterpret_cast<const bf16x8*>(ah + i * 32);
        #pragma unroll
        for (int i = 0; i < 8; ++i) bufB[i] = *reinterpret_cast<const bf16x8*>(ah + 256 + i * 32);
        #pragma unroll
        for (int i = 0; i < 8; ++i) {
            f32x4& acc = (i & 1) ? accB : accA;
            acc = MFMA(bufA[i], wreg[4 + i], acc);
        }
        #pragma unroll
        for (int i = 0; i < 8; ++i) bufA[i] = *reinterpret_cast<const bf16x8*>(ah + 512 + i * 32);
        #pragma unroll
        for (int i = 0; i < 8; ++i) {
            f32x4& acc = (i & 1) ? accB : accA;
            acc = MFMA(bufB[i], wreg[12 + i], acc);
        }
        #pragma unroll
        for (int i = 0; i < 8; ++i) bufB[i] = *reinterpret_cast<const bf16x8*>(ah + 768 + i * 32);
        #pragma unroll
        for (int i = 0; i < 8; ++i) {
            f32x4& acc = (i & 1) ? accB : accA;
            acc = MFMA(bufA[i], wreg[20 + i], acc);
        }
        #pragma unroll
        for (int i = 0; i < 8; ++i) {
            f32x4& acc = (i & 1) ? accB : accA;
            acc = MFMA(bufB[i], wreg[28 + i], acc);
        }

        // ---- epilogue: activations, cross-gate exchange, state update ----
        #pragma unroll
        for (int r = 0; r < 4; ++r) {
            float pre = accA[r] + accB[r];
            float s   = 1.0f / (1.0f + __expf((g == 3) ? -2.0f * pre : -pre));
            float act = (g == 3) ? 2.0f * s - 1.0f : s;
            float x1 = __shfl_xor(act, 1);
            float x2 = __shfl_xor(act, 2);
            float x3 = __shfl_xor(x1, 2);
            float fv = (g == 0) ? act : (g == 1) ? x1 : (g == 2) ? x2 : x3;
            int gi = g ^ 1;
            float iv = (gi == 0) ? act : (gi == 1) ? x1 : (gi == 2) ? x2 : x3;
            int gz = g ^ 2;
            float zv = (gz == 0) ? act : (gz == 1) ? x1 : (gz == 2) ? x2 : x3;
            int gr = g ^ 3;
            float rv = (gr == 0) ? act : (gr == 1) ? x1 : (gr == 2) ? x2 : x3;

            float cn = fv * cst[r] + iv * rv;
            cst[r] = cn;
            float th = 2.0f / (1.0f + __expf(-2.0f * cn)) - 1.0f;
            float hn = zv * th;
            if (g == 0)
                hT[(mi * 16 + quad * 4 + r) * 16 + nj * 4 + (l15 >> 2)] = f2bf(hn);
        }

        __syncthreads();                       // B2: LDS h-tile visible

        // ---- wave0: coalesced write-through of the 32x16 tile (1 KB) ----
        if (wave == 0) {
            const int rowL = lane >> 1, c8 = (lane & 1) * 8;
            const unsigned long long* lp =
                reinterpret_cast<const unsigned long long*>(&hT[rowL * 16 + c8]);
            unsigned long long lo = lp[0], hi = lp[1];
            size_t base = (size_t)(t + 1) * (B_ * H_)
                        + (size_t)(gb * 32 + rowL) * H_ + gh * 16 + c8;
            __hip_atomic_store((unsigned long long*)&Hall[base],     lo,
                               __ATOMIC_RELAXED, __HIP_MEMORY_SCOPE_AGENT);
            __hip_atomic_store((unsigned long long*)&Hall[base + 4], hi,
                               __ATOMIC_RELAXED, __HIP_MEMORY_SCOPE_AGENT);
            __builtin_amdgcn_s_waitcnt(0);     // drain this wave's stores
            asm volatile("" ::: "memory");     // keep flag store after waitcnt
            if (lane == 0)
                __hip_atomic_store(&Flag[((size_t)(t + 1) * GB + gb) * 64 + gh], 1,
                                   __ATOMIC_RELAXED, __HIP_MEMORY_SCOPE_AGENT);
        }
    }
}

// ---------------------------------------------------------------------------
// y[b][t][o] = Hall[t+1][b][:] @ Wob[o][:] + bout[o]
// ---------------------------------------------------------------------------
__global__ void __launch_bounds__(256, 2)
out_gemm(const unsigned short* __restrict__ Hall,
         const unsigned short* __restrict__ Wob,
         const float* __restrict__ bout,
         float* __restrict__ y)
{
    const int tid  = threadIdx.x, wave = tid >> 6, lane = tid & 63;
    const int quad = lane >> 4, l15 = lane & 15;
    const int R    = blockIdx.x * 64 + wave * 16;      // flat row t*128+b

    f32x4 acc[4];
    #pragma unroll
    for (int nt = 0; nt < 4; ++nt) {
        float bb = bout[nt * 16 + l15];
        acc[nt] = {bb, bb, bb, bb};
    }
    const unsigned short* ap = Hall + (size_t)(R + l15 + B_) * H_ + quad * 8;
    #pragma unroll 4
    for (int kk = 0; kk < 32; ++kk) {
        bf16x8 av = *reinterpret_cast<const bf16x8*>(ap + kk * 32);
        #pragma unroll
        for (int nt = 0; nt < 4; ++nt) {
            bf16x8 bv = *reinterpret_cast<const bf16x8*>(
                Wob + (size_t)(nt * 16 + l15) * H_ + kk * 32 + quad * 8);
            acc[nt] = MFMA(av, bv, acc[nt]);
        }
    }
    #pragma unroll
    for (int nt = 0; nt < 4; ++nt)
        #pragma unroll
        for (int r = 0; r < 4; ++r) {
            int row = R + quad * 4 + r;
            int b = row & 127, t = row >> 7;
            y[((size_t)b << 15) + ((size_t)t << 6) + nt * 16 + l15] = acc[nt][r];
        }
}

// ---------------------------------------------------------------------------
extern "C" void kernel_launch(void* const* d_in, const int* in_sizes, int n_in,
                              void* d_out, int out_size, void* d_ws, size_t ws_size,
                              hipStream_t stream)
{
    const float* u    = (const float*)d_in[0];
    const float* x0   = (const float*)d_in[1];
    const float* kfiz = (const float*)d_in[2];
    const float* bfiz = (const float*)d_in[3];
    const float* kr   = (const float*)d_in[4];
    const float* br   = (const float*)d_in[5];
    const float* wo   = (const float*)d_in[6];
    const float* bo   = (const float*)d_in[7];
    float* y = (float*)d_out;

    char* ws = (char*)d_ws;
    size_t off = 0;
    unsigned short* Wp    = (unsigned short*)(ws + off); off += (size_t)4096 * KTOT * 2;        // 9,437,184
    float*          biasp = (float*)(ws + off);          off += (size_t)4096 * 4;               // 16,384
    unsigned short* Wob   = (unsigned short*)(ws + off); off += (size_t)OUT_ * H_ * 2;          // 131,072
    unsigned short* Ubf   = (unsigned short*)(ws + off); off += (size_t)T_ * B_ * IN_ * 2;      // 16,777,216
    unsigned short* Hall  = (unsigned short*)(ws + off); off += (size_t)(T_ + 1) * B_ * H_ * 2; // 134,479,872
    int*            Flag  = (int*)(ws + off);            off += (size_t)(T_ + 1) * GB * 64 * 4; // 525,312
    if (off > ws_size) return;   // workspace too small: deterministic visible failure

    hipMemsetAsync(Flag, 0, (size_t)(T_ + 1) * GB * 64 * 4, stream);
    hipLaunchKernelGGL(pack_weights, dim3(4096),  dim3(256), 0, stream, kfiz, kr, bfiz, br, Wp, biasp);
    hipLaunchKernelGGL(pack_u,       dim3(32768), dim3(256), 0, stream, u, Ubf);
    hipLaunchKernelGGL(pack_wout,    dim3(64),    dim3(256), 0, stream, wo, Wob);

    void* args[] = { (void*)&x0, (void*)&Wp, (void*)&biasp, (void*)&Ubf, (void*)&Hall, (void*)&Flag };
    hipLaunchCooperativeKernel((void*)lstm_scan, dim3(GB * GH), dim3(512), args, 0, stream);

    hipLaunchKernelGGL(out_gemm, dim3((T_ * B_) / 64), dim3(256), 0, stream, Hall, Wob, bo, y);
}

// Round 5
// 2753.548 us; speedup vs baseline: 1.9211x; 1.9211x over previous
//
#include <hip/hip_runtime.h>
#include <hip/hip_bf16.h>

// Problem constants
#define B_    128
#define T_    512
#define IN_   128
#define H_    1024
#define OUT_  64
#define KTOT  1152          // IN_ + H_
#define GH    64            // hidden groups (16 units, 64 gate cols each)
#define GB    4             // batch groups (32 rows each)

typedef short bf16x8 __attribute__((ext_vector_type(8)));
typedef float f32x4  __attribute__((ext_vector_type(4)));

#define MFMA(a,b,c) __builtin_amdgcn_mfma_f32_16x16x32_bf16((a),(b),(c),0,0,0)

__device__ __forceinline__ unsigned short f2bf(float x) {
    unsigned int xi = __float_as_uint(x);
    unsigned int r  = (xi + 0x7fffu + ((xi >> 16) & 1u)) >> 16;
    return (unsigned short)r;
}

// ---------------------------------------------------------------------------
// Pack combined recurrent weights: Wp[c][k] bf16, c = gh*64 + unit_local*4 + gate
// gate 0,1,2 = f,i,z (kernel_fiz col gate*H + j); gate 3 = r (kernel_r col j)
// ---------------------------------------------------------------------------
__global__ void pack_weights(const float* __restrict__ kfiz, const float* __restrict__ kr,
                             const float* __restrict__ bfiz, const float* __restrict__ br,
                             unsigned short* __restrict__ Wp, float* __restrict__ biasp)
{
    const int c    = blockIdx.x;            // 0..4095
    const int gh   = c >> 6, nl = c & 63;
    const int j    = gh * 16 + (nl >> 2);
    const int gate = nl & 3;
    for (int k = threadIdx.x; k < KTOT; k += 256) {
        float v = (gate < 3) ? kfiz[(size_t)k * 3072 + gate * 1024 + j]
                             : kr[(size_t)k * 1024 + j];
        Wp[(size_t)c * KTOT + k] = f2bf(v);
    }
    if (threadIdx.x == 0)
        biasp[c] = (gate < 3) ? bfiz[gate * 1024 + j] : br[j];
}

// u (B,T,IN) fp32 -> Ubf (T,B,IN) bf16
__global__ void pack_u(const float* __restrict__ u, unsigned short* __restrict__ Ubf)
{
    size_t i = (size_t)blockIdx.x * 256 + threadIdx.x;   // < 8388608
    int t = (int)(i >> 14);
    int rem = (int)(i & 16383);
    int b = rem >> 7, k = rem & 127;
    Ubf[i] = f2bf(u[((size_t)b << 16) + ((size_t)t << 7) + k]);
}

// W_out (H,OUT) fp32 -> Wob[o][k] bf16
__global__ void pack_wout(const float* __restrict__ wo, unsigned short* __restrict__ Wob)
{
    const int o = blockIdx.x;               // 0..63
    for (int k = threadIdx.x; k < H_; k += 256)
        Wob[(size_t)o * H_ + k] = f2bf(wo[(size_t)k * OUT_ + o]);
}

// ---------------------------------------------------------------------------
// Persistent recurrent scan. Grid = 256 WGs x 512 threads (cooperative, 1/CU).
// WG (gb,gh): batch rows [gb*32,+32), gate cols [gh*64,+64).
// XCD swizzle: gb = (bid&7)>>1 -> each gb group lives on one XCD pair.
// K-SPLIT waves: wave w -> mi = w&1 (16-row half), nj = w>>1 (K-slice of 288).
// Each wave computes PARTIAL pre-activations for all 64 cols over its K-slice
// (A-traffic per CU: 72 KB/step, disjoint across waves -> no L1 thrash).
// Partials reduced via LDS; owner wave (mi, tile=nj) reduces, adds bias, runs
// the epilogue for cols [nj*16, +16).
// Weights: 36 x f32x4 per wave, pinned with asm to defeat rematerialization.
// Sync: per-WG flag words; wave0 polls the 64 producer flags in parallel.
// ---------------------------------------------------------------------------
__global__ void __launch_bounds__(512, 2)
lstm_scan(const float* __restrict__ x0,
          const unsigned short* __restrict__ Wp,
          const float* __restrict__ biasp,
          const unsigned short* __restrict__ Ubf,
          unsigned short* __restrict__ Hall,
          int* __restrict__ Flag)
{
    __shared__ float part[4 * 8 * 320];       // [nj][mi*4+tl][col*20 + row] 40 KB
    __shared__ unsigned short hT[32 * 16];    // 1 KB h-tile for coalesced publish

    const int tid  = threadIdx.x;
    const int bid  = blockIdx.x;
    const int gb   = (bid & 7) >> 1;                 // XCD-pair -> one gb group
    const int gh   = ((bid & 1) << 5) | (bid >> 3);  // 0..63, unique per gb
    const int wave = tid >> 6;
    const int lane = tid & 63;
    const int mi   = wave & 1;
    const int nj   = wave >> 1;               // K-slice AND owner-tile index, 0..3
    const int quad = lane >> 4;
    const int l15  = lane & 15;
    const int g    = l15 & 3;                 // gate id of this lane's column

    // Weights: tile tl cols gh*64+tl*16+l15, K-slice nj chunks kk (9 x 32).
    f32x4 wregf[36];
    #pragma unroll
    for (int tl = 0; tl < 4; ++tl)
        #pragma unroll
        for (int kk = 0; kk < 9; ++kk)
            wregf[tl * 9 + kk] = *reinterpret_cast<const f32x4*>(
                Wp + (size_t)(gh * 64 + tl * 16 + l15) * KTOT + nj * 288 + kk * 32 + quad * 8);
    #pragma unroll
    for (int i = 0; i < 36; ++i)
        asm volatile("" : "+v"(wregf[i]));    // pin: no remat, keep in VGPRs

    const float bias = biasp[gh * 64 + nj * 16 + l15];   // owner-role bias

    const int rowBase = gb * 32 + mi * 16;
    const int j       = gh * 16 + nj * 4 + (l15 >> 2);   // owner-role unit col

    // c-state (fp32, replicated across the 4 gate lanes of each unit)
    float cst[4];
    #pragma unroll
    for (int r = 0; r < 4; ++r)
        cst[r] = x0[(size_t)(rowBase + quad * 4 + r) * 2048 + 1024 + j];

    // h0 -> Hall[0] (write-through; one-time)
    {
        int m = tid >> 4, uu = tid & 15;      // 512 threads, 512 elems
        int b = gb * 32 + m, jj = gh * 16 + uu;
        unsigned short hv = f2bf(x0[(size_t)b * 2048 + jj]);
        __hip_atomic_store(&Hall[(size_t)b * H_ + jj], hv,
                           __ATOMIC_RELAXED, __HIP_MEMORY_SCOPE_AGENT);
    }
    __syncthreads();                           // vmcnt(0) drain per wave
    if (tid == 0)
        __hip_atomic_store(&Flag[(size_t)gb * 64 + gh], 1,
                           __ATOMIC_RELAXED, __HIP_MEMORY_SCOPE_AGENT);

    const int aRow = rowBase + l15;            // A-frag row (batch index)
    const unsigned short* aU  = Ubf  + (size_t)aRow * IN_ + quad * 8;
    const unsigned short* aHb = Hall + (size_t)aRow * H_  + quad * 8;

    const int kk0 = (nj == 0) ? 4 : 0;         // post-poll chunk start

    for (int t = 0; t < T_; ++t) {
        f32x4 acc[4] = {{0.f,0.f,0.f,0.f},{0.f,0.f,0.f,0.f},
                        {0.f,0.f,0.f,0.f},{0.f,0.f,0.f,0.f}};

        // ---- pre-poll u-part (nj==0 waves own K-chunks 0..3 = u) ----
        if (nj == 0) {
            const unsigned short* au = aU + (size_t)t * (B_ * IN_);
            #pragma unroll
            for (int kk = 0; kk < 4; ++kk) {
                bf16x8 av = *reinterpret_cast<const bf16x8*>(au + kk * 32);
                #pragma unroll
                for (int tl = 0; tl < 4; ++tl)
                    acc[tl] = MFMA(av, __builtin_bit_cast(bf16x8, wregf[tl * 9 + kk]), acc[tl]);
            }
        }

        // ---- wait for h[t]: 64-lane parallel flag poll (reads only) ----
        if (wave == 0) {
            const int* fp = Flag + ((size_t)t * GB + gb) * 64 + lane;
            int v = __hip_atomic_load(fp, __ATOMIC_RELAXED, __HIP_MEMORY_SCOPE_AGENT);
            while (!__all(v != 0))
                v = __hip_atomic_load(fp, __ATOMIC_RELAXED, __HIP_MEMORY_SCOPE_AGENT);
        }
        __syncthreads();                       // B1

        // ---- h-part: this wave's K-slice (disjoint A-loads) ----
        const unsigned short* ah = aHb + (size_t)t * (B_ * H_);
        bf16x8 a[9];
        #pragma unroll
        for (int kk = 0; kk < 9; ++kk)
            if (kk >= kk0)
                a[kk] = *reinterpret_cast<const bf16x8*>(ah + (nj * 288 - 128 + kk * 32));
        #pragma unroll
        for (int kk = 0; kk < 9; ++kk)
            if (kk >= kk0) {
                #pragma unroll
                for (int tl = 0; tl < 4; ++tl)
                    acc[tl] = MFMA(a[kk], __builtin_bit_cast(bf16x8, wregf[tl * 9 + kk]), acc[tl]);
            }

        // ---- write partials to LDS: part[nj][mi*4+tl][col l15][rows quad*4..] ----
        #pragma unroll
        for (int tl = 0; tl < 4; ++tl)
            *reinterpret_cast<f32x4*>(
                &part[(nj * 8 + mi * 4 + tl) * 320 + l15 * 20 + quad * 4]) = acc[tl];
        __syncthreads();                       // B2a

        // ---- owner reduce (this wave owns tile tl == nj for row-half mi) ----
        f32x4 s = {bias, bias, bias, bias};
        {
            const int rbase = (mi * 4 + nj) * 320 + l15 * 20 + quad * 4;
            #pragma unroll
            for (int njj = 0; njj < 4; ++njj)
                s += *reinterpret_cast<const f32x4*>(&part[njj * 2560 + rbase]);
        }

        // ---- epilogue: activations, cross-gate exchange, state update ----
        #pragma unroll
        for (int r = 0; r < 4; ++r) {
            float pre = s[r];
            float sg  = 1.0f / (1.0f + __expf((g == 3) ? -2.0f * pre : -pre));
            float act = (g == 3) ? 2.0f * sg - 1.0f : sg;
            float x1 = __shfl_xor(act, 1);
            float x2 = __shfl_xor(act, 2);
            float x3 = __shfl_xor(x1, 2);
            float fv = (g == 0) ? act : (g == 1) ? x1 : (g == 2) ? x2 : x3;
            int gi = g ^ 1;
            float iv = (gi == 0) ? act : (gi == 1) ? x1 : (gi == 2) ? x2 : x3;
            int gz = g ^ 2;
            float zv = (gz == 0) ? act : (gz == 1) ? x1 : (gz == 2) ? x2 : x3;
            int gr = g ^ 3;
            float rv = (gr == 0) ? act : (gr == 1) ? x1 : (gr == 2) ? x2 : x3;

            float cn = fv * cst[r] + iv * rv;
            cst[r] = cn;
            float th = 2.0f / (1.0f + __expf(-2.0f * cn)) - 1.0f;
            float hn = zv * th;
            if (g == 0)
                hT[(mi * 16 + quad * 4 + r) * 16 + nj * 4 + (l15 >> 2)] = f2bf(hn);
        }

        __syncthreads();                       // B2b: hT complete

        // ---- wave0: coalesced write-through of the 32x16 tile + flag ----
        if (wave == 0) {
            const int rowL = lane >> 1, c8 = (lane & 1) * 8;
            const unsigned long long* lp =
                reinterpret_cast<const unsigned long long*>(&hT[rowL * 16 + c8]);
            unsigned long long lo = lp[0], hi = lp[1];
            size_t base = (size_t)(t + 1) * (B_ * H_)
                        + (size_t)(gb * 32 + rowL) * H_ + gh * 16 + c8;
            __hip_atomic_store((unsigned long long*)&Hall[base],     lo,
                               __ATOMIC_RELAXED, __HIP_MEMORY_SCOPE_AGENT);
            __hip_atomic_store((unsigned long long*)&Hall[base + 4], hi,
                               __ATOMIC_RELAXED, __HIP_MEMORY_SCOPE_AGENT);
            __builtin_amdgcn_s_waitcnt(0);     // drain this wave's stores
            asm volatile("" ::: "memory");
            if (lane == 0)
                __hip_atomic_store(&Flag[((size_t)(t + 1) * GB + gb) * 64 + gh], 1,
                                   __ATOMIC_RELAXED, __HIP_MEMORY_SCOPE_AGENT);
        }
    }
}

// ---------------------------------------------------------------------------
// y[b][t][o] = Hall[t+1][b][:] @ Wob[o][:] + bout[o]
// ---------------------------------------------------------------------------
__global__ void __launch_bounds__(256, 2)
out_gemm(const unsigned short* __restrict__ Hall,
         const unsigned short* __restrict__ Wob,
         const float* __restrict__ bout,
         float* __restrict__ y)
{
    const int tid  = threadIdx.x, wave = tid >> 6, lane = tid & 63;
    const int quad = lane >> 4, l15 = lane & 15;
    const int R    = blockIdx.x * 64 + wave * 16;      // flat row t*128+b

    f32x4 acc[4];
    #pragma unroll
    for (int nt = 0; nt < 4; ++nt) {
        float bb = bout[nt * 16 + l15];
        acc[nt] = {bb, bb, bb, bb};
    }
    const unsigned short* ap = Hall + (size_t)(R + l15 + B_) * H_ + quad * 8;
    #pragma unroll 4
    for (int kk = 0; kk < 32; ++kk) {
        bf16x8 av = *reinterpret_cast<const bf16x8*>(ap + kk * 32);
        #pragma unroll
        for (int nt = 0; nt < 4; ++nt) {
            bf16x8 bv = *reinterpret_cast<const bf16x8*>(
                Wob + (size_t)(nt * 16 + l15) * H_ + kk * 32 + quad * 8);
            acc[nt] = MFMA(av, bv, acc[nt]);
        }
    }
    #pragma unroll
    for (int nt = 0; nt < 4; ++nt)
        #pragma unroll
        for (int r = 0; r < 4; ++r) {
            int row = R + quad * 4 + r;
            int b = row & 127, t = row >> 7;
            y[((size_t)b << 15) + ((size_t)t << 6) + nt * 16 + l15] = acc[nt][r];
        }
}

// ---------------------------------------------------------------------------
extern "C" void kernel_launch(void* const* d_in, const int* in_sizes, int n_in,
                              void* d_out, int out_size, void* d_ws, size_t ws_size,
                              hipStream_t stream)
{
    const float* u    = (const float*)d_in[0];
    const float* x0   = (const float*)d_in[1];
    const float* kfiz = (const float*)d_in[2];
    const float* bfiz = (const float*)d_in[3];
    const float* kr   = (const float*)d_in[4];
    const float* br   = (const float*)d_in[5];
    const float* wo   = (const float*)d_in[6];
    const float* bo   = (const float*)d_in[7];
    float* y = (float*)d_out;

    char* ws = (char*)d_ws;
    size_t off = 0;
    unsigned short* Wp    = (unsigned short*)(ws + off); off += (size_t)4096 * KTOT * 2;        // 9,437,184
    float*          biasp = (float*)(ws + off);          off += (size_t)4096 * 4;               // 16,384
    unsigned short* Wob   = (unsigned short*)(ws + off); off += (size_t)OUT_ * H_ * 2;          // 131,072
    unsigned short* Ubf   = (unsigned short*)(ws + off); off += (size_t)T_ * B_ * IN_ * 2;      // 16,777,216
    unsigned short* Hall  = (unsigned short*)(ws + off); off += (size_t)(T_ + 1) * B_ * H_ * 2; // 134,479,872
    int*            Flag  = (int*)(ws + off);            off += (size_t)(T_ + 1) * GB * 64 * 4; // 525,312
    if (off > ws_size) return;   // workspace too small: deterministic visible failure

    hipMemsetAsync(Flag, 0, (size_t)(T_ + 1) * GB * 64 * 4, stream);
    hipLaunchKernelGGL(pack_weights, dim3(4096),  dim3(256), 0, stream, kfiz, kr, bfiz, br, Wp, biasp);
    hipLaunchKernelGGL(pack_u,       dim3(32768), dim3(256), 0, stream, u, Ubf);
    hipLaunchKernelGGL(pack_wout,    dim3(64),    dim3(256), 0, stream, wo, Wob);

    void* args[] = { (void*)&x0, (void*)&Wp, (void*)&biasp, (void*)&Ubf, (void*)&Hall, (void*)&Flag };
    hipLaunchCooperativeKernel((void*)lstm_scan, dim3(GB * GH), dim3(512), args, 0, stream);

    hipLaunchKernelGGL(out_gemm, dim3((T_ * B_) / 64), dim3(256), 0, stream, Hall, Wob, bo, y);
}